// Round 1
// 426.342 us; speedup vs baseline: 1.0694x; 1.0694x over previous
//
#include <hip/hip_runtime.h>
#include <stdint.h>

#define S 2048
#define HID 4096
#define NKV 8
#define HD 128
#define KV 1024
#define BATCH 2
#define NQKV 3072   // KV*3 (q_eff | k | v)
#define MROWS 4096  // B*S

typedef __attribute__((ext_vector_type(4))) float f32x4;
typedef __attribute__((ext_vector_type(8))) __bf16 bf16x8;
typedef __attribute__((ext_vector_type(8))) unsigned short ushort8;
typedef __attribute__((ext_vector_type(4))) unsigned short ushort4_t;
typedef __attribute__((ext_vector_type(4))) float float4_t;

// fp32 -> bf16 bits, round-to-nearest-even
__device__ __forceinline__ unsigned short f2bf(float f) {
    unsigned int u = __builtin_bit_cast(unsigned int, f);
    u += 0x7fffu + ((u >> 16) & 1u);
    return (unsigned short)(u >> 16);
}
__device__ __forceinline__ float bf2f(unsigned short s) {
    unsigned int u = ((unsigned int)s) << 16;
    return __builtin_bit_cast(float, u);
}

// async global->LDS, 16B per lane. LDS dest must be wave-uniform base + lane*16.
__device__ __forceinline__ void gl2lds16(const void* g, void* l) {
    __builtin_amdgcn_global_load_lds(
        (const __attribute__((address_space(1))) void*)(uintptr_t)(g),
        (__attribute__((address_space(3))) void*)(uintptr_t)(l),
        16, 0, 0);
}

// ---------------------------------------------------------------- cast x->bf16
__global__ __launch_bounds__(256) void castx_kernel(const float* __restrict__ x,
                                                    unsigned short* __restrict__ xb) {
    int i = (blockIdx.x * 256 + threadIdx.x) * 4;
    float4_t v = *(const float4_t*)&x[i];
    ushort4_t o;
    o.x = f2bf(v.x); o.y = f2bf(v.y); o.z = f2bf(v.z); o.w = f2bf(v.w);
    *(ushort4_t*)&xb[i] = o;
}

// ------------------------------------------- build WcatT[3072][4096] bf16
__global__ __launch_bounds__(256) void wcat_kernel(const float* __restrict__ wq,
                                                   const float* __restrict__ wk,
                                                   const float* __restrict__ wv,
                                                   unsigned short* __restrict__ WcatT) {
    __shared__ float T[64 * 65];
    const int tid = threadIdx.x;
    const int k0 = blockIdx.x * 64;
    const int n0 = blockIdx.y * 64;
    const float scale = 0.088388347648318447f;  // 1/sqrt(128)
#pragma unroll
    for (int i = 0; i < 16; i++) {
        int kl = (tid >> 6) + i * 4;
        int nl = tid & 63;
        int k = k0 + kl, n = n0 + nl;
        float v;
        if (n < KV) {
            int kvh = n >> 7, d = n & 127;
            const float* p = wq + (size_t)k * HID + kvh * 512 + d;
            v = (p[0] + p[128] + p[256] + p[384]) * scale;
        } else if (n < 2048) {
            v = wk[(size_t)k * KV + (n - KV)];
        } else {
            v = wv[(size_t)k * KV + (n - 2048)];
        }
        T[kl * 65 + nl] = v;
    }
    __syncthreads();
#pragma unroll
    for (int i = 0; i < 16; i++) {
        int nl = (tid >> 6) + i * 4;
        int kl = tid & 63;
        WcatT[(size_t)(n0 + nl) * HID + k0 + kl] = f2bf(T[kl * 65 + nl]);
    }
}

// ------------------------------------------- build woT[4096][1024] bf16 (wo^T)
__global__ __launch_bounds__(256) void wot_kernel(const float* __restrict__ wo,
                                                  unsigned short* __restrict__ woT) {
    __shared__ float T[64 * 65];
    const int tid = threadIdx.x;
    const int k0 = blockIdx.x * 64;
    const int n0 = blockIdx.y * 64;
#pragma unroll
    for (int i = 0; i < 16; i++) {
        int kl = (tid >> 6) + i * 4, nl = tid & 63;
        T[kl * 65 + nl] = wo[(size_t)(k0 + kl) * HID + n0 + nl];
    }
    __syncthreads();
#pragma unroll
    for (int i = 0; i < 16; i++) {
        int nl = (tid >> 6) + i * 4, kl = tid & 63;
        woT[(size_t)(n0 + nl) * KV + k0 + kl] = f2bf(T[kl * 65 + nl]);
    }
}

// ============================================================================
// 256x256 8-phase GEMM (T2+T3+T4+T5): C[M][N] = A[M][K] * Bt[N][K]^T, bf16 in.
// 512 thr / 8 waves (2M x 4N); per-wave C = 128x64. BK=64, 2 K-tiles per iter.
// LDS: 2 dbuf x 2 row-halves x [128][64] for A and B = 128 KiB -> 1 block/CU.
// LDS layout per half: 16 subtiles of [16 rows][32 cols] (1024B each), with
// st_16x32 swizzle: byte ^= ((byte>>9)&1)<<5. gload_lds dest stays LINEAR;
// the swizzle is applied by permuting the global SOURCE chunk (involution)
// and XORing the ds_read address (rule 21: both-sides-or-neither).
// Phases (per K-tile, quadrants of per-wave C, K=64 each = 16 MFMA):
//   P1: read A[mi0-3]+B[ni0-1] (12 ds_read_b128), MFMA Q(0,0)
//   P2: read B[ni2-3] (4),                        MFMA Q(0,2)
//   P3: read A[mi4-7] (8),                        MFMA Q(4,2)
//   P4: no reads,                                 MFMA Q(4,0)
// Staging: 1 half-tile (2 x global_load_lds) per phase. buf0's next tile in
// P4-P7 (buf0 reads end at P3's trailing barrier -> no WAR race), buf1's in
// P8..P3. vmcnt(2) at P4/P8 end retires exactly the 8 loads of the tile
// consumed next; 2 loads always stay in flight (counted, never 0).
// ============================================================================
#define BAR() do { asm volatile("" ::: "memory"); __builtin_amdgcn_s_barrier(); asm volatile("" ::: "memory"); } while (0)
#define WAITV2() asm volatile("s_waitcnt vmcnt(2)" ::: "memory")

__device__ __forceinline__ void stage2(const unsigned short* __restrict__ g,
                                       size_t so0, size_t so1,
                                       unsigned short* lds, int tid) {
    gl2lds16(g + so0, lds + (size_t)tid * 8);
    gl2lds16(g + so1, lds + (size_t)(512 + tid) * 8);
}

template <int OUT_BF16>
__global__ __launch_bounds__(512, 2) void gemm_bt8(const unsigned short* __restrict__ A,
                                                   const unsigned short* __restrict__ Bt,
                                                   void* __restrict__ Cv,
                                                   int M, int N, int K) {
    __shared__ unsigned short As[2][2][8192];
    __shared__ unsigned short Bs[2][2][8192];
    const int tid = threadIdx.x;
    const int lane = tid & 63, wave = tid >> 6;
    const int lm = lane & 15, quad = lane >> 4;
    const int wm = wave >> 2;            // M-half of the block this wave owns
    const int wn = wave & 3;             // N quarter
    const int wnh = wn >> 1;             // B row-half
    const int wnb = (wn & 1) * 4;        // B subtile row-group base within half

    // ---- XCD-aware bijective block swizzle (nwg % 8 == 0 for both call sites)
    const int nbx = gridDim.x;
    const int id = blockIdx.y * nbx + blockIdx.x;
    const int cpx = (nbx * gridDim.y) >> 3;
    const int sid = (id & 7) * cpx + (id >> 3);
    const int m0 = (sid / nbx) * 256;
    const int n0 = (sid % nbx) * 256;

    // ---- staging source offsets (inverse-st_16x32-swizzled global chunks)
    // chunk p (16B): LDS byte = p*16 (linear). Natural subtiled coords of the
    // data that must land there: psrc = p ^ (((p>>5)&1)<<1)  [byte bit9 -> bit5]
    size_t so0, so1;
    {
#pragma unroll
        for (int i = 0; i < 2; i++) {
            int p = i * 512 + tid;
            int ps = p ^ (((p >> 5) & 1) << 1);
            int s = ps >> 6, w = ps & 63;
            int row = ((s >> 1) << 4) + (w >> 2);
            int kc = ((s & 1) << 5) + ((w & 3) << 3);
            size_t off = (size_t)row * K + kc;
            if (i == 0) so0 = off; else so1 = off;
        }
    }
    const unsigned short* Agb = A + (size_t)m0 * K;
    const unsigned short* Bgb = Bt + (size_t)n0 * K;
    const size_t hK = (size_t)128 * K;

    // ---- ds_read address: subtile s = rg*2+kk; within: lm*32 + swizzled col
    const int roff = lm * 32 + ((quad << 3) ^ (((lm >> 3) & 1) << 4));

#define LDA(mi, kk, BUF) a[(mi) & 3][kk] = *(const bf16x8*)&As[BUF][wm][(((mi) * 2 + (kk)) << 9) + roff]
#define LDB(ni, kk, BUF) b[ni][kk] = *(const bf16x8*)&Bs[BUF][wnh][(((wnb + (ni)) * 2 + (kk)) << 9) + roff]
#define RD_A_LO(BUF) { LDA(0,0,BUF); LDA(0,1,BUF); LDA(1,0,BUF); LDA(1,1,BUF); LDA(2,0,BUF); LDA(2,1,BUF); LDA(3,0,BUF); LDA(3,1,BUF); }
#define RD_A_HI(BUF) { LDA(4,0,BUF); LDA(4,1,BUF); LDA(5,0,BUF); LDA(5,1,BUF); LDA(6,0,BUF); LDA(6,1,BUF); LDA(7,0,BUF); LDA(7,1,BUF); }
#define RD_B_LO(BUF) { LDB(0,0,BUF); LDB(0,1,BUF); LDB(1,0,BUF); LDB(1,1,BUF); }
#define RD_B_HI(BUF) { LDB(2,0,BUF); LDB(2,1,BUF); LDB(3,0,BUF); LDB(3,1,BUF); }
#define MFMA_Q(MB, NB) do { \
    __builtin_amdgcn_s_setprio(1); \
    _Pragma("unroll") for (int i_ = 0; i_ < 4; i_++) \
    _Pragma("unroll") for (int j_ = 0; j_ < 2; j_++) \
    _Pragma("unroll") for (int k_ = 0; k_ < 2; k_++) \
        acc[(MB) + i_][(NB) + j_] = __builtin_amdgcn_mfma_f32_16x16x32_bf16( \
            a[i_][k_], b[(NB) + j_][k_], acc[(MB) + i_][(NB) + j_], 0, 0, 0); \
    __builtin_amdgcn_s_setprio(0); \
} while (0)

    f32x4 acc[8][4] = {};
    bf16x8 a[4][2], b[4][2];

    const int KT = K >> 6;   // 64-wide K-tiles
    const int NT = KT >> 1;  // iterations (2 tiles each)

    // ---- prologue: tile0 -> buf0 (4 halves), tile1.A0 -> buf1
    stage2(Agb, so0, so1, &As[0][0][0], tid);
    stage2(Agb + hK, so0, so1, &As[0][1][0], tid);
    stage2(Bgb, so0, so1, &Bs[0][0][0], tid);
    stage2(Bgb + hK, so0, so1, &Bs[0][1][0], tid);
    stage2(Agb + 64, so0, so1, &As[1][0][0], tid);
    WAITV2();  // 10 outstanding -> retire 8 = tile0 complete; tile1.A0 in flight
    BAR();

    for (int t = 0; t < NT; ++t) {
        const int t1 = 2 * t + 1;
        int t2 = 2 * t + 2; if (t2 >= KT) t2 = KT - 1;  // tail: harmless restage
        int t3 = 2 * t + 3; if (t3 >= KT) t3 = KT - 1;
        const size_t k1 = (size_t)t1 * 64, k2 = (size_t)t2 * 64, k3 = (size_t)t3 * 64;

        // P1: buf0 reads (A-lo + B-lo); stage buf1.A1 <- t1
        RD_A_LO(0); RD_B_LO(0);
        stage2(Agb + hK + k1, so0, so1, &As[1][1][0], tid);
        BAR(); MFMA_Q(0, 0); BAR();

        // P2: buf0 B-hi; stage buf1.B0 <- t1
        RD_B_HI(0);
        stage2(Bgb + k1, so0, so1, &Bs[1][0][0], tid);
        BAR(); MFMA_Q(0, 2); BAR();

        // P3: buf0 A-hi; stage buf1.B1 <- t1
        RD_A_HI(0);
        stage2(Bgb + hK + k1, so0, so1, &Bs[1][1][0], tid);
        BAR(); MFMA_Q(4, 2); BAR();

        // P4: no reads; stage buf0.A0 <- t2 (buf0 reads ended at P3 barrier)
        stage2(Agb + k2, so0, so1, &As[0][0][0], tid);
        BAR(); MFMA_Q(4, 0);
        WAITV2();  // retire t1's 4 halves; P4 stage stays in flight
        BAR();

        // P5: buf1 reads (A-lo + B-lo); stage buf0.A1 <- t2
        RD_A_LO(1); RD_B_LO(1);
        stage2(Agb + hK + k2, so0, so1, &As[0][1][0], tid);
        BAR(); MFMA_Q(0, 0); BAR();

        // P6: buf1 B-hi; stage buf0.B0 <- t2
        RD_B_HI(1);
        stage2(Bgb + k2, so0, so1, &Bs[0][0][0], tid);
        BAR(); MFMA_Q(0, 2); BAR();

        // P7: buf1 A-hi; stage buf0.B1 <- t2
        RD_A_HI(1);
        stage2(Bgb + hK + k2, so0, so1, &Bs[0][1][0], tid);
        BAR(); MFMA_Q(4, 2); BAR();

        // P8: no reads; stage buf1.A0 <- t3 (buf1 reads ended at P7 barrier)
        stage2(Agb + k3, so0, so1, &As[1][0][0], tid);
        BAR(); MFMA_Q(4, 0);
        WAITV2();  // retire t2's 4 halves; P8 stage stays in flight
        BAR();
    }

    // ---- epilogue: C write (D layout: row = quad*4+r, col = lm; verified)
    const int crow0 = m0 + wm * 128 + quad * 4;
    const int ccol0 = n0 + wn * 64 + lm;
#pragma unroll
    for (int mi = 0; mi < 8; mi++)
#pragma unroll
        for (int ni = 0; ni < 4; ni++)
#pragma unroll
            for (int r = 0; r < 4; r++) {
                const int row = crow0 + mi * 16 + r;
                const int col = ccol0 + ni * 16;
                if (OUT_BF16)
                    ((unsigned short*)Cv)[(size_t)row * N + col] = f2bf(acc[mi][ni][r]);
                else
                    ((float*)Cv)[(size_t)row * N + col] = acc[mi][ni][r];
            }
#undef LDA
#undef LDB
#undef RD_A_LO
#undef RD_A_HI
#undef RD_B_LO
#undef RD_B_HI
#undef MFMA_Q
}

// ------------------------------------------- Vt[(b*8+h)*128 + d][s] from QKV v-part
__global__ __launch_bounds__(256) void vt_kernel(const unsigned short* __restrict__ QKV,
                                                 unsigned short* __restrict__ Vt) {
    __shared__ unsigned short T[128 * 136];
    const int tid = threadIdx.x;
    const int st = blockIdx.x;
    const int bh = blockIdx.y;
    const int b = bh >> 3, h = bh & 7;
#pragma unroll
    for (int it = 0; it < 8; it++) {
        int chunk = tid + it * 256;
        int s = chunk >> 4, cc = chunk & 15;
        ushort8 v = *(const ushort8*)&QKV[(size_t)(b * S + st * 128 + s) * NQKV + 2048 + h * HD + cc * 8];
        *(ushort8*)&T[s * 136 + cc * 8] = v;
    }
    __syncthreads();
#pragma unroll
    for (int it = 0; it < 8; it++) {
        int chunk = tid + it * 256;
        int d = chunk >> 4, scc = chunk & 15;
        ushort8 o;
#pragma unroll
        for (int j = 0; j < 8; j++) o[j] = T[(scc * 8 + j) * 136 + d];
        *(ushort8*)&Vt[(size_t)((b * NKV + h) * HD + d) * S + st * 128 + scc * 8] = o;
    }
}

// ------------------------------------------- attention v2 (unchanged)
__global__ __launch_bounds__(256, 1) void attn_kernel(const unsigned short* __restrict__ QKV,
                                                      const unsigned short* __restrict__ Vt,
                                                      unsigned short* __restrict__ Oout) {
    __shared__ unsigned short Ks[64 * 128];
    __shared__ unsigned short Vs[128 * 64];
    __shared__ unsigned short Ps[128 * 64];
    const int tid = threadIdx.x;
    const int lane = tid & 63, wave = tid >> 6;
    const int lm = lane & 15, quad = lane >> 4;
    const int sw = lm & 7;
    const int qt = blockIdx.x;
    const int h = blockIdx.y;
    const int b = blockIdx.z;
    const int qrow0 = qt * 128 + wave * 32;

    bf16x8 qf[2][4];
#pragma unroll
    for (int rt = 0; rt < 2; rt++)
#pragma unroll
        for (int ks = 0; ks < 4; ks++) {
            size_t off = (size_t)(b * S + qrow0 + rt * 16 + lm) * NQKV + h * HD + ks * 32 + quad * 8;
            qf[rt][ks] = *(const bf16x8*)&QKV[off];
        }

    float lsum[2][4] = {};
    f32x4 oacc[2][8] = {};

    const int krow = tid >> 2, kc4 = tid & 3;
    const int vrow = tid >> 1, vc2 = tid & 1;
    const unsigned short* Kg0 = QKV + (size_t)(b * S) * NQKV + KV + h * HD + kc4 * 32;
    const unsigned short* Vg0 = Vt + (size_t)((b * NKV + h) * HD + vrow) * S + vc2 * 32;

    ushort8 kreg[4], vreg[4];
    {
        const unsigned short* kg = Kg0 + (size_t)krow * NQKV;
        const unsigned short* vg = Vg0;
#pragma unroll
        for (int j = 0; j < 4; j++) kreg[j] = *(const ushort8*)(kg + j * 8);
#pragma unroll
        for (int j = 0; j < 4; j++) vreg[j] = *(const ushort8*)(vg + j * 8);
    }

    for (int kt = 0; kt < 32; kt++) {
        __syncthreads();
#pragma unroll
        for (int j = 0; j < 4; j++)
            *(ushort8*)&Ks[krow * 128 + ((kc4 * 4 + j) ^ (krow & 7)) * 8] = kreg[j];
#pragma unroll
        for (int j = 0; j < 4; j++)
            *(ushort8*)&Vs[vrow * 64 + ((vc2 * 4 + j) ^ (vrow & 7)) * 8] = vreg[j];
        __syncthreads();
        if (kt < 31) {
            const unsigned short* kg = Kg0 + (size_t)((kt + 1) * 64 + krow) * NQKV;
            const unsigned short* vg = Vg0 + (kt + 1) * 64;
#pragma unroll
            for (int j = 0; j < 4; j++) kreg[j] = *(const ushort8*)(kg + j * 8);
#pragma unroll
            for (int j = 0; j < 4; j++) vreg[j] = *(const ushort8*)(vg + j * 8);
        }

        f32x4 sc[2][4] = {};
#pragma unroll
        for (int ks = 0; ks < 4; ks++)
#pragma unroll
            for (int ct = 0; ct < 4; ct++) {
                bf16x8 kf = *(const bf16x8*)&Ks[(ct * 16 + lm) * 128 + ((ks * 4 + quad) ^ sw) * 8];
                sc[0][ct] = __builtin_amdgcn_mfma_f32_16x16x32_bf16(qf[0][ks], kf, sc[0][ct], 0, 0, 0);
                sc[1][ct] = __builtin_amdgcn_mfma_f32_16x16x32_bf16(qf[1][ks], kf, sc[1][ct], 0, 0, 0);
            }

#pragma unroll
        for (int rt = 0; rt < 2; rt++)
#pragma unroll
            for (int ct = 0; ct < 4; ct++)
#pragma unroll
                for (int r = 0; r < 4; r++) {
                    float p = __expf(fminf(sc[rt][ct][r], 60.f));
                    unsigned short pb = f2bf(p);
                    lsum[rt][r] += bf2f(pb);
                    int prow = wave * 32 + rt * 16 + quad * 4 + r;
                    int pcol = ct * 16 + lm;
                    Ps[prow * 64 + (((pcol >> 3) ^ (prow & 7)) * 8) + (pcol & 7)] = pb;
                }

#pragma unroll
        for (int ks = 0; ks < 2; ks++) {
            bf16x8 af0 = *(const bf16x8*)&Ps[(wave * 32 + lm) * 64 + ((ks * 4 + quad) ^ sw) * 8];
            bf16x8 af1 = *(const bf16x8*)&Ps[(wave * 32 + 16 + lm) * 64 + ((ks * 4 + quad) ^ sw) * 8];
#pragma unroll
            for (int dt = 0; dt < 8; dt++) {
                bf16x8 vf = *(const bf16x8*)&Vs[(dt * 16 + lm) * 64 + ((ks * 4 + quad) ^ sw) * 8];
                oacc[0][dt] = __builtin_amdgcn_mfma_f32_16x16x32_bf16(af0, vf, oacc[0][dt], 0, 0, 0);
                oacc[1][dt] = __builtin_amdgcn_mfma_f32_16x16x32_bf16(af1, vf, oacc[1][dt], 0, 0, 0);
            }
        }
    }

#pragma unroll
    for (int rt = 0; rt < 2; rt++)
#pragma unroll
        for (int r = 0; r < 4; r++) {
            float v = lsum[rt][r];
            v += __shfl_xor(v, 8);
            v += __shfl_xor(v, 4);
            v += __shfl_xor(v, 2);
            v += __shfl_xor(v, 1);
            lsum[rt][r] = v;
        }
#pragma unroll
    for (int rt = 0; rt < 2; rt++)
#pragma unroll
        for (int dt = 0; dt < 8; dt++)
#pragma unroll
            for (int r = 0; r < 4; r++) {
                int row = b * S + qt * 128 + wave * 32 + rt * 16 + quad * 4 + r;
                int col = h * HD + dt * 16 + lm;
                Oout[(size_t)row * KV + col] = f2bf(oacc[rt][dt][r] / lsum[rt][r]);
            }
}

// ----------------------------------------------------------------------------
extern "C" void kernel_launch(void* const* d_in, const int* in_sizes, int n_in,
                              void* d_out, int out_size, void* d_ws, size_t ws_size,
                              hipStream_t stream) {
    (void)in_sizes; (void)n_in; (void)out_size; (void)ws_size;
    const float* x  = (const float*)d_in[0];
    const float* wq = (const float*)d_in[1];
    const float* wk = (const float*)d_in[2];
    const float* wv = (const float*)d_in[3];
    const float* wo = (const float*)d_in[4];
    float* out = (float*)d_out;
    char* ws = (char*)d_ws;

    unsigned short* xb    = (unsigned short*)(ws);                         // 33.5MB
    unsigned short* WcatT = (unsigned short*)(ws + 33554432);              // 25.2MB
    unsigned short* woT   = (unsigned short*)(ws + 33554432 + 25165824);   // 8.4MB
    unsigned short* QKV   = (unsigned short*)(ws + 67108864);              // 25.2MB
    unsigned short* Vt    = (unsigned short*)(ws);                         // aliases dead xb
    unsigned short* AttnO = (unsigned short*)(ws + 8388608);               // aliases dead xb

    castx_kernel<<<16384, 256, 0, stream>>>(x, xb);
    wcat_kernel<<<dim3(64, 48), 256, 0, stream>>>(wq, wk, wv, WcatT);
    wot_kernel<<<dim3(16, 64), 256, 0, stream>>>(wo, woT);
    gemm_bt8<1><<<dim3(NQKV / 256, MROWS / 256), 512, 0, stream>>>(xb, WcatT, QKV, MROWS, NQKV, HID);
    vt_kernel<<<dim3(16, 16), 256, 0, stream>>>(QKV, Vt);
    attn_kernel<<<dim3(16, NKV, BATCH), 256, 0, stream>>>(QKV, Vt, AttnO);
    gemm_bt8<0><<<dim3(HID / 256, MROWS / 256), 512, 0, stream>>>(AttnO, woT, out, MROWS, HID, KV);
}

// Round 2
// 423.268 us; speedup vs baseline: 1.0772x; 1.0073x over previous
//
#include <hip/hip_runtime.h>
#include <stdint.h>

#define S 2048
#define HID 4096
#define NKV 8
#define HD 128
#define KV 1024
#define BATCH 2
#define NQKV 3072   // KV*3 (q_eff | k | v)
#define MROWS 4096  // B*S

typedef __attribute__((ext_vector_type(4))) float f32x4;
typedef __attribute__((ext_vector_type(8))) __bf16 bf16x8;
typedef __attribute__((ext_vector_type(8))) unsigned short ushort8;
typedef __attribute__((ext_vector_type(4))) unsigned short ushort4_t;
typedef __attribute__((ext_vector_type(4))) float float4_t;

// fp32 -> bf16 bits, round-to-nearest-even
__device__ __forceinline__ unsigned short f2bf(float f) {
    unsigned int u = __builtin_bit_cast(unsigned int, f);
    u += 0x7fffu + ((u >> 16) & 1u);
    return (unsigned short)(u >> 16);
}
__device__ __forceinline__ float bf2f(unsigned short s) {
    unsigned int u = ((unsigned int)s) << 16;
    return __builtin_bit_cast(float, u);
}

// async global->LDS, 16B per lane. LDS dest must be wave-uniform base + lane*16.
__device__ __forceinline__ void gl2lds16(const void* g, void* l) {
    __builtin_amdgcn_global_load_lds(
        (const __attribute__((address_space(1))) void*)(uintptr_t)(g),
        (__attribute__((address_space(3))) void*)(uintptr_t)(l),
        16, 0, 0);
}

// ---------------------------------------------------------------- cast x->bf16
__global__ __launch_bounds__(256) void castx_kernel(const float* __restrict__ x,
                                                    unsigned short* __restrict__ xb) {
    int i = (blockIdx.x * 256 + threadIdx.x) * 4;
    float4_t v = *(const float4_t*)&x[i];
    ushort4_t o;
    o.x = f2bf(v.x); o.y = f2bf(v.y); o.z = f2bf(v.z); o.w = f2bf(v.w);
    *(ushort4_t*)&xb[i] = o;
}

// ------------------------------------------- build WcatT[3072][4096] bf16
__global__ __launch_bounds__(256) void wcat_kernel(const float* __restrict__ wq,
                                                   const float* __restrict__ wk,
                                                   const float* __restrict__ wv,
                                                   unsigned short* __restrict__ WcatT) {
    __shared__ float T[64 * 65];
    const int tid = threadIdx.x;
    const int k0 = blockIdx.x * 64;
    const int n0 = blockIdx.y * 64;
    const float scale = 0.088388347648318447f;  // 1/sqrt(128)
#pragma unroll
    for (int i = 0; i < 16; i++) {
        int kl = (tid >> 6) + i * 4;
        int nl = tid & 63;
        int k = k0 + kl, n = n0 + nl;
        float v;
        if (n < KV) {
            int kvh = n >> 7, d = n & 127;
            const float* p = wq + (size_t)k * HID + kvh * 512 + d;
            v = (p[0] + p[128] + p[256] + p[384]) * scale;
        } else if (n < 2048) {
            v = wk[(size_t)k * KV + (n - KV)];
        } else {
            v = wv[(size_t)k * KV + (n - 2048)];
        }
        T[kl * 65 + nl] = v;
    }
    __syncthreads();
#pragma unroll
    for (int i = 0; i < 16; i++) {
        int nl = (tid >> 6) + i * 4;
        int kl = tid & 63;
        WcatT[(size_t)(n0 + nl) * HID + k0 + kl] = f2bf(T[kl * 65 + nl]);
    }
}

// ------------------------------------------- build woT[4096][1024] bf16 (wo^T)
__global__ __launch_bounds__(256) void wot_kernel(const float* __restrict__ wo,
                                                  unsigned short* __restrict__ woT) {
    __shared__ float T[64 * 65];
    const int tid = threadIdx.x;
    const int k0 = blockIdx.x * 64;
    const int n0 = blockIdx.y * 64;
#pragma unroll
    for (int i = 0; i < 16; i++) {
        int kl = (tid >> 6) + i * 4, nl = tid & 63;
        T[kl * 65 + nl] = wo[(size_t)(k0 + kl) * HID + n0 + nl];
    }
    __syncthreads();
#pragma unroll
    for (int i = 0; i < 16; i++) {
        int nl = (tid >> 6) + i * 4, kl = tid & 63;
        woT[(size_t)(n0 + nl) * KV + k0 + kl] = f2bf(T[kl * 65 + nl]);
    }
}

// ============================================================================
// 256x256 8-phase GEMM (T2+T3+T4+T5): C[M][N] = A[M][K] * Bt[N][K]^T, bf16 in.
// 512 thr / 8 waves (2M x 4N); per-wave C = 128x64. BK=64, 2 K-tiles per iter.
// LDS: 2 dbuf x 2 row-halves x [128][64] for A and B = 128 KiB -> 1 block/CU.
// st_16x32 swizzle via inverse-permuted global SOURCE + XORed ds_read address
// (gload_lds dest stays linear; rule 21 both-sides-or-neither).
//
// Quarter-granularity staging, 3-phase-deep (m201's vmcnt(6) = 3 half-tiles
// in flight). Per phase: 2 gload_lds (one 64-row quarter per A/B half).
//   p1: stage buf1.A-hi <- t(2t+1)   [read p7 this iter; covered by p4 wait]
//   p2..p5: stage buf0.{A-lo,B-lo,B-hi,A-hi} <- t(2t+2)  [read next p1-p3;
//           covered by p8 wait]
//   p6..p8: stage buf1.{A-lo,B-lo,B-hi} <- t(2t+3) [covered by next p4 wait]
// WAR per slot: each stage issues strictly after the phase that last ds_reads
// the old contents (A-lo read p1, B-lo p1, B-hi p2, A-hi p3 / +4 for buf1).
// vmcnt(6) at p4/p8 end: leaves exactly the 3 most recent stages in flight,
// guarantees the 4 quarters consumed next are complete. Never drains to 0.
// ============================================================================
#define BAR() do { asm volatile("" ::: "memory"); __builtin_amdgcn_s_barrier(); asm volatile("" ::: "memory"); } while (0)
#define WAITV6() asm volatile("s_waitcnt vmcnt(6)" ::: "memory")

template <int OUT_BF16>
__global__ __launch_bounds__(512, 2) void gemm_bt8(const unsigned short* __restrict__ A,
                                                   const unsigned short* __restrict__ Bt,
                                                   void* __restrict__ Cv,
                                                   int M, int N, int K) {
    __shared__ unsigned short As[2][2][8192];
    __shared__ unsigned short Bs[2][2][8192];
    const int tid = threadIdx.x;
    const int lane = tid & 63, wave = tid >> 6;
    const int lm = lane & 15, quad = lane >> 4;
    const int wm = wave >> 2;            // M-half of the block this wave owns
    const int wn = wave & 3;             // N quarter
    const int wnh = wn >> 1;             // B row-half
    const int wnb = (wn & 1) * 4;        // B subtile row-group base within half

    // ---- XCD-aware bijective block swizzle (nwg % 8 == 0 for both call sites)
    const int nbx = gridDim.x;
    const int id = blockIdx.y * nbx + blockIdx.x;
    const int cpx = (nbx * gridDim.y) >> 3;
    const int sid = (id & 7) * cpx + (id >> 3);
    const int m0 = (sid / nbx) * 256;
    const int n0 = (sid % nbx) * 256;

    // ---- staging source offsets (inverse-st_16x32-swizzled global chunks)
    // chunk p (16B): LDS byte = p*16 (linear). psrc = p ^ (((p>>5)&1)<<1)
    size_t so0, so1;
    {
#pragma unroll
        for (int i = 0; i < 2; i++) {
            int p = i * 512 + tid;
            int ps = p ^ (((p >> 5) & 1) << 1);
            int s = ps >> 6, w = ps & 63;
            int row = ((s >> 1) << 4) + (w >> 2);
            int kc = ((s & 1) << 5) + ((w & 3) << 3);
            size_t off = (size_t)row * K + kc;
            if (i == 0) so0 = off; else so1 = off;
        }
    }
    const unsigned short* Agb = A + (size_t)m0 * K;
    const unsigned short* Bgb = Bt + (size_t)n0 * K;
    const size_t hK = (size_t)128 * K;

// stage one 64-row quarter (8KB) of a [128][64] LDS half; G = half base ptr
#define STLO(G, L) gl2lds16((G) + so0, (L) + (size_t)tid * 8)
#define STHI(G, L) gl2lds16((G) + so1, (L) + (size_t)(512 + tid) * 8)

    // ---- ds_read address: subtile s = rg*2+kk; within: lm*32 + swizzled col
    const int roff = lm * 32 + ((quad << 3) ^ (((lm >> 3) & 1) << 4));

#define LDA(mi, kk, BUF) a[(mi) & 3][kk] = *(const bf16x8*)&As[BUF][wm][(((mi) * 2 + (kk)) << 9) + roff]
#define LDB(ni, kk, BUF) b[ni][kk] = *(const bf16x8*)&Bs[BUF][wnh][(((wnb + (ni)) * 2 + (kk)) << 9) + roff]
#define RD_A_LO(BUF) { LDA(0,0,BUF); LDA(0,1,BUF); LDA(1,0,BUF); LDA(1,1,BUF); LDA(2,0,BUF); LDA(2,1,BUF); LDA(3,0,BUF); LDA(3,1,BUF); }
#define RD_A_HI(BUF) { LDA(4,0,BUF); LDA(4,1,BUF); LDA(5,0,BUF); LDA(5,1,BUF); LDA(6,0,BUF); LDA(6,1,BUF); LDA(7,0,BUF); LDA(7,1,BUF); }
#define RD_B_LO(BUF) { LDB(0,0,BUF); LDB(0,1,BUF); LDB(1,0,BUF); LDB(1,1,BUF); }
#define RD_B_HI(BUF) { LDB(2,0,BUF); LDB(2,1,BUF); LDB(3,0,BUF); LDB(3,1,BUF); }
#define MFMA_Q(MB, NB) do { \
    __builtin_amdgcn_s_setprio(1); \
    _Pragma("unroll") for (int i_ = 0; i_ < 4; i_++) \
    _Pragma("unroll") for (int j_ = 0; j_ < 2; j_++) \
    _Pragma("unroll") for (int k_ = 0; k_ < 2; k_++) \
        acc[(MB) + i_][(NB) + j_] = __builtin_amdgcn_mfma_f32_16x16x32_bf16( \
            a[i_][k_], b[(NB) + j_][k_], acc[(MB) + i_][(NB) + j_], 0, 0, 0); \
    __builtin_amdgcn_s_setprio(0); \
} while (0)

    f32x4 acc[8][4] = {};
    bf16x8 a[4][2], b[4][2];

    const int KT = K >> 6;   // 64-wide K-tiles
    const int NT = KT >> 1;  // iterations (2 tiles each)

    // ---- prologue: tile0 -> buf0 (8 quarters), tile1 -> buf1 (A-lo,B-lo,B-hi)
    STLO(Agb, &As[0][0][0]); STLO(Agb + hK, &As[0][1][0]);
    STHI(Agb, &As[0][0][0]); STHI(Agb + hK, &As[0][1][0]);
    STLO(Bgb, &Bs[0][0][0]); STLO(Bgb + hK, &Bs[0][1][0]);
    STHI(Bgb, &Bs[0][0][0]); STHI(Bgb + hK, &Bs[0][1][0]);
    STLO(Agb + 64, &As[1][0][0]); STLO(Agb + hK + 64, &As[1][1][0]);
    STLO(Bgb + 64, &Bs[1][0][0]); STLO(Bgb + hK + 64, &Bs[1][1][0]);
    STHI(Bgb + 64, &Bs[1][0][0]); STHI(Bgb + hK + 64, &Bs[1][1][0]);
    WAITV6();  // 14 outstanding -> retire 8 = tile0 complete; tile1's 6 in flight
    BAR();

    for (int t = 0; t < NT; ++t) {
        const size_t k1 = (size_t)(2 * t + 1) * 64;
        int t2i = 2 * t + 2; if (t2i >= KT) t2i = KT - 1;  // tail: harmless restage
        int t3i = 2 * t + 3; if (t3i >= KT) t3i = KT - 1;
        const size_t k2 = (size_t)t2i * 64, k3 = (size_t)t3i * 64;

        // P1: buf0 A-lo+B-lo reads; stage buf1.A-hi <- t1
        RD_A_LO(0); RD_B_LO(0);
        STHI(Agb + k1, &As[1][0][0]); STHI(Agb + hK + k1, &As[1][1][0]);
        BAR(); MFMA_Q(0, 0); BAR();

        // P2: buf0 B-hi; stage buf0.A-lo <- t2 (old A-lo read at P1)
        RD_B_HI(0);
        STLO(Agb + k2, &As[0][0][0]); STLO(Agb + hK + k2, &As[0][1][0]);
        BAR(); MFMA_Q(0, 2); BAR();

        // P3: buf0 A-hi; stage buf0.B-lo <- t2 (old B-lo read at P1)
        RD_A_HI(0);
        STLO(Bgb + k2, &Bs[0][0][0]); STLO(Bgb + hK + k2, &Bs[0][1][0]);
        BAR(); MFMA_Q(4, 2); BAR();

        // P4: stage buf0.B-hi <- t2 (old read at P2); wait -> buf1 complete
        STHI(Bgb + k2, &Bs[0][0][0]); STHI(Bgb + hK + k2, &Bs[0][1][0]);
        BAR(); MFMA_Q(4, 0);
        WAITV6();  // retire through P1's stage: all of buf1/t1 resident
        BAR();

        // P5: buf1 A-lo+B-lo reads; stage buf0.A-hi <- t2 (old read at P3)
        RD_A_LO(1); RD_B_LO(1);
        STHI(Agb + k2, &As[0][0][0]); STHI(Agb + hK + k2, &As[0][1][0]);
        BAR(); MFMA_Q(0, 0); BAR();

        // P6: buf1 B-hi; stage buf1.A-lo <- t3 (old read at P5)
        RD_B_HI(1);
        STLO(Agb + k3, &As[1][0][0]); STLO(Agb + hK + k3, &As[1][1][0]);
        BAR(); MFMA_Q(0, 2); BAR();

        // P7: buf1 A-hi; stage buf1.B-lo <- t3 (old read at P5)
        RD_A_HI(1);
        STLO(Bgb + k3, &Bs[1][0][0]); STLO(Bgb + hK + k3, &Bs[1][1][0]);
        BAR(); MFMA_Q(4, 2); BAR();

        // P8: stage buf1.B-hi <- t3 (old read at P6); wait -> buf0 complete
        STHI(Bgb + k3, &Bs[1][0][0]); STHI(Bgb + hK + k3, &Bs[1][1][0]);
        BAR(); MFMA_Q(4, 0);
        WAITV6();  // retire through P5's stage: all of buf0/t2 resident
        BAR();
    }

    // ---- epilogue: C write (D layout: row = quad*4+r, col = lm)
    const int crow0 = m0 + wm * 128 + quad * 4;
    const int ccol0 = n0 + wn * 64 + lm;
#pragma unroll
    for (int mi = 0; mi < 8; mi++)
#pragma unroll
        for (int ni = 0; ni < 4; ni++)
#pragma unroll
            for (int r = 0; r < 4; r++) {
                const int row = crow0 + mi * 16 + r;
                const int col = ccol0 + ni * 16;
                if (OUT_BF16)
                    ((unsigned short*)Cv)[(size_t)row * N + col] = f2bf(acc[mi][ni][r]);
                else
                    ((float*)Cv)[(size_t)row * N + col] = acc[mi][ni][r];
            }
#undef LDA
#undef LDB
#undef RD_A_LO
#undef RD_A_HI
#undef RD_B_LO
#undef RD_B_HI
#undef MFMA_Q
#undef STLO
#undef STHI
}

// ------------------------------------------- Vt[(b*8+h)*128 + d][s] from QKV v-part
__global__ __launch_bounds__(256) void vt_kernel(const unsigned short* __restrict__ QKV,
                                                 unsigned short* __restrict__ Vt) {
    __shared__ unsigned short T[128 * 136];
    const int tid = threadIdx.x;
    const int st = blockIdx.x;
    const int bh = blockIdx.y;
    const int b = bh >> 3, h = bh & 7;
#pragma unroll
    for (int it = 0; it < 8; it++) {
        int chunk = tid + it * 256;
        int s = chunk >> 4, cc = chunk & 15;
        ushort8 v = *(const ushort8*)&QKV[(size_t)(b * S + st * 128 + s) * NQKV + 2048 + h * HD + cc * 8];
        *(ushort8*)&T[s * 136 + cc * 8] = v;
    }
    __syncthreads();
#pragma unroll
    for (int it = 0; it < 8; it++) {
        int chunk = tid + it * 256;
        int d = chunk >> 4, scc = chunk & 15;
        ushort8 o;
#pragma unroll
        for (int j = 0; j < 8; j++) o[j] = T[(scc * 8 + j) * 136 + d];
        *(ushort8*)&Vt[(size_t)((b * NKV + h) * HD + d) * S + st * 128 + scc * 8] = o;
    }
}

// ------------------------------------------- attention v3
// QBLK=64: grid (h, qt, b) = 8 x 32 x 2 = 512 blocks, 2 blocks/CU
// (launch_bounds(256,2), LDS 40KB) -> 2 waves/SIMD so one block's softmax
// VALU overlaps the other's MFMA. h fastest in grid -> all qt-blocks of a
// head land on one XCD (K/V 2MB/XCD, L2-resident).
// 4 waves x 16 q-rows. 64-key tiles, 32 iters. K/V reg-staged, 1-iter prefetch.
__global__ __launch_bounds__(256, 2) void attn_kernel(const unsigned short* __restrict__ QKV,
                                                      const unsigned short* __restrict__ Vt,
                                                      unsigned short* __restrict__ Oout) {
    __shared__ unsigned short Ks[64 * 128];
    __shared__ unsigned short Vs[128 * 64];
    __shared__ unsigned short Ps[64 * 64];
    const int tid = threadIdx.x;
    const int lane = tid & 63, wave = tid >> 6;
    const int lm = lane & 15, quad = lane >> 4;
    const int sw = lm & 7;
    const int h = blockIdx.x;
    const int qt = blockIdx.y;
    const int b = blockIdx.z;
    const int qrow0 = qt * 64 + wave * 16;

    // Q fragments (A-layout: A[m=lm][k=quad*8+j]), scale already in wq_eff
    bf16x8 qf[4];
#pragma unroll
    for (int ks = 0; ks < 4; ks++) {
        size_t off = (size_t)(b * S + qrow0 + lm) * NQKV + h * HD + ks * 32 + quad * 8;
        qf[ks] = *(const bf16x8*)&QKV[off];
    }

    float lsum[4] = {};
    f32x4 oacc[8] = {};

    const int krow = tid >> 2, kc4 = tid & 3;
    const int vrow = tid >> 1, vc2 = tid & 1;
    const unsigned short* Kg0 = QKV + (size_t)(b * S) * NQKV + KV + h * HD + kc4 * 32;
    const unsigned short* Vg0 = Vt + (size_t)((b * NKV + h) * HD + vrow) * S + vc2 * 32;

    ushort8 kreg[4], vreg[4];
    {
        const unsigned short* kg = Kg0 + (size_t)krow * NQKV;
        const unsigned short* vg = Vg0;
#pragma unroll
        for (int j = 0; j < 4; j++) kreg[j] = *(const ushort8*)(kg + j * 8);
#pragma unroll
        for (int j = 0; j < 4; j++) vreg[j] = *(const ushort8*)(vg + j * 8);
    }

    for (int kt = 0; kt < 32; kt++) {
        __syncthreads();  // prior-iter LDS reads done; prefetch drained (needed now)
#pragma unroll
        for (int j = 0; j < 4; j++)
            *(ushort8*)&Ks[krow * 128 + ((kc4 * 4 + j) ^ (krow & 7)) * 8] = kreg[j];
#pragma unroll
        for (int j = 0; j < 4; j++)
            *(ushort8*)&Vs[vrow * 64 + ((vc2 * 4 + j) ^ (vrow & 7)) * 8] = vreg[j];
        __syncthreads();
        if (kt < 31) {  // prefetch next tile; overlaps all compute below
            const unsigned short* kg = Kg0 + (size_t)((kt + 1) * 64 + krow) * NQKV;
            const unsigned short* vg = Vg0 + (kt + 1) * 64;
#pragma unroll
            for (int j = 0; j < 4; j++) kreg[j] = *(const ushort8*)(kg + j * 8);
#pragma unroll
            for (int j = 0; j < 4; j++) vreg[j] = *(const ushort8*)(vg + j * 8);
        }

        // S = Q K^T : per wave 16q x 64k
        f32x4 sc[4] = {};
#pragma unroll
        for (int ks = 0; ks < 4; ks++)
#pragma unroll
            for (int ct = 0; ct < 4; ct++) {
                bf16x8 kf = *(const bf16x8*)&Ks[(ct * 16 + lm) * 128 + ((ks * 4 + quad) ^ sw) * 8];
                sc[ct] = __builtin_amdgcn_mfma_f32_16x16x32_bf16(qf[ks], kf, sc[ct], 0, 0, 0);
            }

        // p = exp(s); accumulate l from the bf16-rounded p (matches PV weights)
#pragma unroll
        for (int ct = 0; ct < 4; ct++)
#pragma unroll
            for (int r = 0; r < 4; r++) {
                float p = __expf(fminf(sc[ct][r], 60.f));
                unsigned short pb = f2bf(p);
                lsum[r] += bf2f(pb);
                int prow = wave * 16 + quad * 4 + r;
                int pcol = ct * 16 + lm;
                Ps[prow * 64 + (((pcol >> 3) ^ (prow & 7)) * 8) + (pcol & 7)] = pb;
            }

        // O += P V (own P rows only -> in-wave DS ordering, no barrier)
#pragma unroll
        for (int ks = 0; ks < 2; ks++) {
            bf16x8 af = *(const bf16x8*)&Ps[(wave * 16 + lm) * 64 + ((ks * 4 + quad) ^ sw) * 8];
#pragma unroll
            for (int dt = 0; dt < 8; dt++) {
                bf16x8 vf = *(const bf16x8*)&Vs[(dt * 16 + lm) * 64 + ((ks * 4 + quad) ^ sw) * 8];
                oacc[dt] = __builtin_amdgcn_mfma_f32_16x16x32_bf16(af, vf, oacc[dt], 0, 0, 0);
            }
        }
    }

    // final l reduction over the 16 lanes holding each row
#pragma unroll
    for (int r = 0; r < 4; r++) {
        float v = lsum[r];
        v += __shfl_xor(v, 8);
        v += __shfl_xor(v, 4);
        v += __shfl_xor(v, 2);
        v += __shfl_xor(v, 1);
        lsum[r] = v;
    }
#pragma unroll
    for (int dt = 0; dt < 8; dt++)
#pragma unroll
        for (int r = 0; r < 4; r++) {
            int row = b * S + qt * 64 + wave * 16 + quad * 4 + r;
            int col = h * HD + dt * 16 + lm;
            Oout[(size_t)row * KV + col] = f2bf(oacc[dt][r] / lsum[r]);
        }
}

// ----------------------------------------------------------------------------
extern "C" void kernel_launch(void* const* d_in, const int* in_sizes, int n_in,
                              void* d_out, int out_size, void* d_ws, size_t ws_size,
                              hipStream_t stream) {
    (void)in_sizes; (void)n_in; (void)out_size; (void)ws_size;
    const float* x  = (const float*)d_in[0];
    const float* wq = (const float*)d_in[1];
    const float* wk = (const float*)d_in[2];
    const float* wv = (const float*)d_in[3];
    const float* wo = (const float*)d_in[4];
    float* out = (float*)d_out;
    char* ws = (char*)d_ws;

    unsigned short* xb    = (unsigned short*)(ws);                         // 33.5MB
    unsigned short* WcatT = (unsigned short*)(ws + 33554432);              // 25.2MB
    unsigned short* woT   = (unsigned short*)(ws + 33554432 + 25165824);   // 8.4MB
    unsigned short* QKV   = (unsigned short*)(ws + 67108864);              // 25.2MB
    unsigned short* Vt    = (unsigned short*)(ws);                         // aliases dead xb
    unsigned short* AttnO = (unsigned short*)(ws + 8388608);               // aliases dead xb

    castx_kernel<<<16384, 256, 0, stream>>>(x, xb);
    wcat_kernel<<<dim3(64, 48), 256, 0, stream>>>(wq, wk, wv, WcatT);
    wot_kernel<<<dim3(16, 64), 256, 0, stream>>>(wo, woT);
    gemm_bt8<1><<<dim3(NQKV / 256, MROWS / 256), 512, 0, stream>>>(xb, WcatT, QKV, MROWS, NQKV, HID);
    vt_kernel<<<dim3(16, 16), 256, 0, stream>>>(QKV, Vt);
    attn_kernel<<<dim3(NKV, 32, BATCH), 256, 0, stream>>>(QKV, Vt, AttnO);
    gemm_bt8<0><<<dim3(HID / 256, MROWS / 256), 512, 0, stream>>>(AttnO, woT, out, MROWS, HID, KV);
}